// Round 3
// baseline (48300.647 us; speedup 1.0000x reference)
//
#include <hip/hip_runtime.h>
#include <hip/hip_fp16.h>
#include <cstdint>

#define T_STEPS 1024
#define BATCH   128
#define DIM     256   // D
#define HID     256   // H
#define FF      128   // F
#define KC      (DIM + HID)   // 512

typedef _Float16 h2 __attribute__((ext_vector_type(2)));

// ws layout:
//   fp16 packed weights (units _Float16):
//     WgP at 0      : [KC/8][4H][8]  = 524288 halfs (1 MB)
//     W1P at 524288 : [4][H/8][F][8] = 131072 halfs (256 KB)
//     W2P at 655360 : [4][F/8][H][8] = 131072 halfs (256 KB)
//   z2 exchange (float): [128 pair][2 s][2 parity][2 gate][256]  at byte 1572864 (1 MB)
//   flags (unsigned): [256]                                      at byte 2621440
#define WGP_OFF 0
#define W1P_OFF 524288
#define W2P_OFF 655360
#define WS_HALFS 786432
#define Z2X_BYTE_OFF  1572864
#define FLAG_BYTE_OFF 2621440
#define WS_SPLIT_BYTES (FLAG_BYTE_OFF + 256 * 4)

__device__ __forceinline__ float sigmoidf_(float x) {
    return 1.0f / (1.0f + __expf(-x));
}
__device__ __forceinline__ float tanhf_(float x) {
    float e = __expf(2.0f * x);
    return 1.0f - 2.0f / (e + 1.0f);
}

__device__ __forceinline__ float fdot2_(h2 a, h2 b, float c) {
#if __has_builtin(__builtin_amdgcn_fdot2)
    return __builtin_amdgcn_fdot2(a, b, c, false);
#else
    return fmaf((float)a.x, (float)b.x, fmaf((float)a.y, (float)b.y, c));
#endif
}

union U4H { uint4 u; h2 h[4]; };

// ---------------- weight convert + repack (fp32 -> fp16, 16B-per-thread tiles) ----------
__global__ __launch_bounds__(256)
void convert_kernel(const float* __restrict__ Wg,
                    const float* __restrict__ W1,
                    const float* __restrict__ W2,
                    _Float16* __restrict__ ws)
{
    int i = blockIdx.x * 256 + threadIdx.x;
    if (i < 524288) {
        int k = i >> 10, c = i & 1023;
        ws[WGP_OFF + (((size_t)(k >> 3) << 10) + c) * 8 + (k & 7)] = (_Float16)Wg[i];
    } else if (i < 655360) {
        int j = i - 524288;           // W1 [4][H][F]
        int g = j >> 15, k = (j >> 7) & 255, f = j & 127;
        ws[W1P_OFF + (((size_t)((g << 5) + (k >> 3)) << 7) + f) * 8 + (k & 7)] = (_Float16)W1[j];
    } else if (i < 786432) {
        int j = i - 655360;           // W2 [4][F][H]
        int g = j >> 15, f = (j >> 8) & 127, h = j & 255;
        ws[W2P_OFF + (((size_t)((g << 4) + (f >> 3)) << 8) + h) * 8 + (f & 7)] = (_Float16)W2[j];
    }
}

__global__ void flaginit_kernel(unsigned* __restrict__ flags) {
    flags[threadIdx.x] = 0u;
}

// ---------------- split recurrence: 2 WGs per batch element (gate pairs) ----------------
// block = (s<<7) | b ; s=0 owns gates {f,i}, s=1 owns {g,o}. One exchange per step.
__global__ __launch_bounds__(512)
void qlstm_split2_kernel(const float* __restrict__ x,
                         const _Float16* __restrict__ ws,
                         float* __restrict__ z2x,
                         unsigned* __restrict__ flags,
                         const float* __restrict__ bg,
                         const float* __restrict__ b1,
                         const float* __restrict__ b2,
                         float* __restrict__ out)
{
    const int blk = blockIdx.x;
    const int b   = blk & 127;
    const int s   = blk >> 7;
    const int tid = threadIdx.x;

    __shared__ _Float16 combh[KC];     // [x | h] fp16 (pairs)
    __shared__ _Float16 zh[512];       // own-half z
    __shared__ _Float16 h1h[256];      // own 2 gates' FFN hidden
    __shared__ float z2loc[512];
    __shared__ float cbuf[HID];
    __shared__ float hbuf[HID];
    __shared__ float bgs[512];
    __shared__ float b1s[256];
    __shared__ float b2s[512];

    bgs[tid] = bg[(s << 9) + tid];
    b2s[tid] = b2[(s << 9) + tid];
    if (tid < 256) b1s[tid] = b1[(s << 8) + tid];
    if (tid < 256) { cbuf[tid] = 0.0f; hbuf[tid] = 0.0f; }
    if (tid < 128) {
        h2 zz; zz.x = (_Float16)0.0f; zz.y = (_Float16)0.0f;
        ((h2*)combh)[128 + tid] = zz;
    }

    const uint4* __restrict__ wgp = reinterpret_cast<const uint4*>(ws + WGP_OFF);
    const uint4* __restrict__ w1p = reinterpret_cast<const uint4*>(ws + W1P_OFF);
    const uint4* __restrict__ w2p = reinterpret_cast<const uint4*>(ws + W2P_OFF);
    const h2* ch2 = reinterpret_cast<const h2*>(combh);

    const unsigned myFlag = (unsigned)blk;
    const unsigned pFlag  = (unsigned)(blk ^ 128);

    for (int t = 0; t < T_STEPS; ++t) {
        __syncthreads();
        if (tid < 128) {
            float2 xv = reinterpret_cast<const float2*>(x + ((size_t)t * BATCH + b) * DIM)[tid];
            h2 hv; hv.x = (_Float16)xv.x; hv.y = (_Float16)xv.y;
            ((h2*)combh)[tid] = hv;
        }
        __syncthreads();

        // ---- phase 1: z cols c = s*512 + tid ----
        {
            const int c = (s << 9) + tid;
            float acc = bgs[tid];
            #pragma unroll 8
            for (int k8 = 0; k8 < 64; ++k8) {
                U4H w; w.u = wgp[(k8 << 10) + c];
                acc = fdot2_(ch2[4 * k8 + 0], w.h[0], acc);
                acc = fdot2_(ch2[4 * k8 + 1], w.h[1], acc);
                acc = fdot2_(ch2[4 * k8 + 2], w.h[2], acc);
                acc = fdot2_(ch2[4 * k8 + 3], w.h[3], acc);
            }
            zh[tid] = (_Float16)acc;
        }
        __syncthreads();

        // ---- phase 2: h1 for own 2 gates (tid < 256) ----
        if (tid < 256) {
            const int gl = tid >> 7, f = tid & 127, gg = (s << 1) + gl;
            const h2* zp = reinterpret_cast<const h2*>(zh + (gl << 8));
            float acc = b1s[tid];
            #pragma unroll 8
            for (int k8 = 0; k8 < 32; ++k8) {
                U4H w; w.u = w1p[(((gg << 5) + k8) << 7) + f];
                acc = fdot2_(zp[4 * k8 + 0], w.h[0], acc);
                acc = fdot2_(zp[4 * k8 + 1], w.h[1], acc);
                acc = fdot2_(zp[4 * k8 + 2], w.h[2], acc);
                acc = fdot2_(zp[4 * k8 + 3], w.h[3], acc);
            }
            h1h[tid] = (_Float16)fmaxf(acc, 0.0f);
        }
        __syncthreads();

        // ---- phase 3: z2 for own 2 gates ----
        {
            const int gl = tid >> 8, hcol = tid & 255, gg = (s << 1) + gl;
            const h2* hp = reinterpret_cast<const h2*>(h1h + (gl << 7));
            float acc = b2s[tid];
            #pragma unroll 8
            for (int f8 = 0; f8 < 16; ++f8) {
                U4H w; w.u = w2p[(((gg << 4) + f8) << 8) + hcol];
                acc = fdot2_(hp[4 * f8 + 0], w.h[0], acc);
                acc = fdot2_(hp[4 * f8 + 1], w.h[1], acc);
                acc = fdot2_(hp[4 * f8 + 2], w.h[2], acc);
                acc = fdot2_(hp[4 * f8 + 3], w.h[3], acc);
            }
            z2loc[tid] = acc;
            float* dst = z2x + ((((size_t)(b * 2 + s) * 2 + (t & 1)) * 2 + gl) << 8) + hcol;
            __hip_atomic_store(dst, acc, __ATOMIC_RELAXED, __HIP_MEMORY_SCOPE_AGENT);
        }
        __threadfence();
        __syncthreads();
        if (tid == 0) {
            __hip_atomic_store(&flags[myFlag], (unsigned)(t + 1), __ATOMIC_RELEASE, __HIP_MEMORY_SCOPE_AGENT);
            while (__hip_atomic_load(&flags[pFlag], __ATOMIC_ACQUIRE, __HIP_MEMORY_SCOPE_AGENT) < (unsigned)(t + 1)) {
                __builtin_amdgcn_s_sleep(4);
            }
        }
        __syncthreads();

        // ---- gate update: tid < 128, cols 2*tid, 2*tid+1 ----
        if (tid < 128) {
            const float* pbase = z2x + ((((size_t)(b * 2 + (s ^ 1)) * 2 + (t & 1)) * 2) << 8);
            const int c0 = 2 * tid, c1 = c0 + 1;
            float pA0 = __hip_atomic_load(pbase + c0,       __ATOMIC_RELAXED, __HIP_MEMORY_SCOPE_AGENT);
            float pA1 = __hip_atomic_load(pbase + c1,       __ATOMIC_RELAXED, __HIP_MEMORY_SCOPE_AGENT);
            float pB0 = __hip_atomic_load(pbase + 256 + c0, __ATOMIC_RELAXED, __HIP_MEMORY_SCOPE_AGENT);
            float pB1 = __hip_atomic_load(pbase + 256 + c1, __ATOMIC_RELAXED, __HIP_MEMORY_SCOPE_AGENT);
            float zf0, zi0, zg0, zo0, zf1, zi1, zg1, zo1;
            if (s == 0) {
                zf0 = z2loc[c0]; zi0 = z2loc[256 + c0]; zg0 = pA0; zo0 = pB0;
                zf1 = z2loc[c1]; zi1 = z2loc[256 + c1]; zg1 = pA1; zo1 = pB1;
            } else {
                zf0 = pA0; zi0 = pB0; zg0 = z2loc[c0]; zo0 = z2loc[256 + c0];
                zf1 = pA1; zi1 = pB1; zg1 = z2loc[c1]; zo1 = z2loc[256 + c1];
            }
            float f0 = sigmoidf_(zf0), i0 = sigmoidf_(zi0), g0 = tanhf_(zg0), o0 = sigmoidf_(zo0);
            float f1 = sigmoidf_(zf1), i1 = sigmoidf_(zi1), g1 = tanhf_(zg1), o1 = sigmoidf_(zo1);
            float cc0 = fmaf(f0, cbuf[c0], i0 * g0);
            float cc1 = fmaf(f1, cbuf[c1], i1 * g1);
            float h0 = o0 * tanhf_(cc0);
            float h1 = o1 * tanhf_(cc1);
            cbuf[c0] = cc0; cbuf[c1] = cc1;
            hbuf[c0] = h0;  hbuf[c1] = h1;
            h2 hv; hv.x = (_Float16)h0; hv.y = (_Float16)h1;
            ((h2*)combh)[128 + tid] = hv;
            if (s == 0) {
                reinterpret_cast<float2*>(out + ((size_t)t * BATCH + b) * HID)[tid] = make_float2(h0, h1);
            }
        }
    }

    __syncthreads();
    if (s == 0 && tid < 256) {
        const size_t TBH = (size_t)T_STEPS * BATCH * HID;
        out[TBH + (size_t)b * HID + tid] = hbuf[tid];
        out[TBH + (size_t)BATCH * HID + (size_t)b * HID + tid] = cbuf[tid];
    }
}

// ---------------- fallback: single-WG-per-element fp16-weight kernel (round 2) ----------
__global__ __launch_bounds__(1024)
void qlstm_fp16w_kernel(const float* __restrict__ x,
                        const _Float16* __restrict__ ws,
                        const float* __restrict__ bg,
                        const float* __restrict__ b1,
                        const float* __restrict__ b2,
                        float* __restrict__ out)
{
    const int b   = blockIdx.x;
    const int tid = threadIdx.x;

    __shared__ float comb[KC];
    __shared__ float zbuf[4 * HID];
    __shared__ float h1buf[4 * FF];
    __shared__ float z2buf[4 * HID];
    __shared__ float cbuf[HID];
    __shared__ float bgs[4 * HID];
    __shared__ float b1s[4 * FF];
    __shared__ float b2s[4 * HID];

    bgs[tid] = bg[tid];
    if (tid < 4 * FF) b1s[tid] = b1[tid];
    b2s[tid] = b2[tid];
    if (tid < HID) { cbuf[tid] = 0.0f; comb[DIM + tid] = 0.0f; }

    const uint4* __restrict__ wgp = reinterpret_cast<const uint4*>(ws + WGP_OFF);
    const uint4* __restrict__ w1p = reinterpret_cast<const uint4*>(ws + W1P_OFF);
    const uint4* __restrict__ w2p = reinterpret_cast<const uint4*>(ws + W2P_OFF);

    for (int t = 0; t < T_STEPS; ++t) {
        __syncthreads();
        if (tid < DIM) comb[tid] = x[((size_t)t * BATCH + b) * DIM + tid];
        __syncthreads();

        {
            const float4* combv = reinterpret_cast<const float4*>(comb);
            float acc = bgs[tid];
            #pragma unroll 8
            for (int k8 = 0; k8 < KC / 8; ++k8) {
                U4H w; w.u = wgp[(k8 << 10) + tid];
                float4 c0 = combv[2 * k8];
                float4 c1 = combv[2 * k8 + 1];
                acc = fmaf(c0.x, (float)w.h[0].x, acc);
                acc = fmaf(c0.y, (float)w.h[0].y, acc);
                acc = fmaf(c0.z, (float)w.h[1].x, acc);
                acc = fmaf(c0.w, (float)w.h[1].y, acc);
                acc = fmaf(c1.x, (float)w.h[2].x, acc);
                acc = fmaf(c1.y, (float)w.h[2].y, acc);
                acc = fmaf(c1.z, (float)w.h[3].x, acc);
                acc = fmaf(c1.w, (float)w.h[3].y, acc);
            }
            zbuf[tid] = acc;
        }
        __syncthreads();

        if (tid < 4 * FF) {
            const int g = tid >> 7, f = tid & 127;
            const float4* zv = reinterpret_cast<const float4*>(zbuf + g * HID);
            float acc = b1s[tid];
            #pragma unroll 8
            for (int k8 = 0; k8 < HID / 8; ++k8) {
                U4H w; w.u = w1p[(((g << 5) + k8) << 7) + f];
                float4 z0 = zv[2 * k8];
                float4 z1 = zv[2 * k8 + 1];
                acc = fmaf(z0.x, (float)w.h[0].x, acc);
                acc = fmaf(z0.y, (float)w.h[0].y, acc);
                acc = fmaf(z0.z, (float)w.h[1].x, acc);
                acc = fmaf(z0.w, (float)w.h[1].y, acc);
                acc = fmaf(z1.x, (float)w.h[2].x, acc);
                acc = fmaf(z1.y, (float)w.h[2].y, acc);
                acc = fmaf(z1.z, (float)w.h[3].x, acc);
                acc = fmaf(z1.w, (float)w.h[3].y, acc);
            }
            h1buf[tid] = fmaxf(acc, 0.0f);
        }
        __syncthreads();

        {
            const int g = tid >> 8, h = tid & 255;
            const float4* hv = reinterpret_cast<const float4*>(h1buf + g * FF);
            float acc = b2s[tid];
            #pragma unroll 8
            for (int f8 = 0; f8 < FF / 8; ++f8) {
                U4H w; w.u = w2p[(((g << 4) + f8) << 8) + h];
                float4 h0 = hv[2 * f8];
                float4 h1 = hv[2 * f8 + 1];
                acc = fmaf(h0.x, (float)w.h[0].x, acc);
                acc = fmaf(h0.y, (float)w.h[0].y, acc);
                acc = fmaf(h0.z, (float)w.h[1].x, acc);
                acc = fmaf(h0.w, (float)w.h[1].y, acc);
                acc = fmaf(h1.x, (float)w.h[2].x, acc);
                acc = fmaf(h1.y, (float)w.h[2].y, acc);
                acc = fmaf(h1.z, (float)w.h[3].x, acc);
                acc = fmaf(h1.w, (float)w.h[3].y, acc);
            }
            z2buf[tid] = acc;
        }
        __syncthreads();

        if (tid < HID) {
            float zf = z2buf[tid];
            float zi = z2buf[HID + tid];
            float zg = z2buf[2 * HID + tid];
            float zo = z2buf[3 * HID + tid];
            float fg = sigmoidf_(zf);
            float ig = sigmoidf_(zi);
            float gg = tanhf_(zg);
            float og = sigmoidf_(zo);
            float c  = fmaf(fg, cbuf[tid], ig * gg);
            float hh = og * tanhf_(c);
            cbuf[tid] = c;
            comb[DIM + tid] = hh;
            out[((size_t)t * BATCH + b) * HID + tid] = hh;
        }
    }

    __syncthreads();
    if (tid < HID) {
        out[(size_t)T_STEPS * BATCH * HID + (size_t)b * HID + tid] = comb[DIM + tid];
        out[(size_t)T_STEPS * BATCH * HID + (size_t)BATCH * HID + (size_t)b * HID + tid] = cbuf[tid];
    }
}

extern "C" void kernel_launch(void* const* d_in, const int* in_sizes, int n_in,
                              void* d_out, int out_size, void* d_ws, size_t ws_size,
                              hipStream_t stream) {
    const float* x  = (const float*)d_in[0];
    const float* Wg = (const float*)d_in[1];
    const float* bg = (const float*)d_in[2];
    const float* W1 = (const float*)d_in[3];
    const float* b1 = (const float*)d_in[4];
    const float* W2 = (const float*)d_in[5];
    const float* b2 = (const float*)d_in[6];
    float* out = (float*)d_out;
    char* wsc = (char*)d_ws;

    if (ws_size >= (size_t)WS_SPLIT_BYTES) {
        _Float16* ws = (_Float16*)wsc;
        float* z2x = (float*)(wsc + Z2X_BYTE_OFF);
        unsigned* flags = (unsigned*)(wsc + FLAG_BYTE_OFF);
        convert_kernel<<<WS_HALFS / 256, 256, 0, stream>>>(Wg, W1, W2, ws);
        flaginit_kernel<<<1, 256, 0, stream>>>(flags);
        qlstm_split2_kernel<<<256, 512, 0, stream>>>(x, ws, z2x, flags, bg, b1, b2, out);
    } else if (ws_size >= (size_t)WS_HALFS * sizeof(_Float16)) {
        _Float16* ws = (_Float16*)wsc;
        convert_kernel<<<WS_HALFS / 256, 256, 0, stream>>>(Wg, W1, W2, ws);
        qlstm_fp16w_kernel<<<BATCH, 1024, 0, stream>>>(x, ws, bg, b1, b2, out);
    }
}

// Round 4
// 9340.746 us; speedup vs baseline: 5.1710x; 5.1710x over previous
//
#include <hip/hip_runtime.h>
#include <hip/hip_fp16.h>
#include <cstdint>

#define T_STEPS 1024
#define BATCH   128
#define DIM     256   // D
#define HID     256   // H
#define FF      128   // F
#define KC      (DIM + HID)   // 512
#define CHUNK   16

typedef _Float16 h2 __attribute__((ext_vector_type(2)));

// ws layout (units _Float16), all fp16 packed for 16B-per-thread loads:
//   WgxP at 0      : [256/8][1024][8] = 262144 halfs (512 KB)   rows k<256 of Wg
//   WghP at 262144 : [256/8][1024][8] = 262144 halfs (512 KB)   rows k>=256 of Wg
//   W1P  at 524288 : [4][H/8][F][8]   = 131072 halfs (256 KB)
//   W2P  at 655360 : [4][F/8][H][8]   = 131072 halfs (256 KB)
#define WGXP_OFF 0
#define WGHP_OFF 262144
#define W1P_OFF  524288
#define W2P_OFF  655360
#define WS_HALFS 786432   // 1.5 MB

__device__ __forceinline__ float sigmoidf_(float x) {
    return 1.0f / (1.0f + __expf(-x));
}
__device__ __forceinline__ float tanhf_(float x) {
    float e = __expf(2.0f * x);
    return 1.0f - 2.0f / (e + 1.0f);
}
__device__ __forceinline__ float fdot2_(h2 a, h2 b, float c) {
#if __has_builtin(__builtin_amdgcn_fdot2)
    return __builtin_amdgcn_fdot2(a, b, c, false);
#else
    return fmaf((float)a.x, (float)b.x, fmaf((float)a.y, (float)b.y, c));
#endif
}

union U4H { uint4 u; h2 h[4]; };

// ---------------- weight convert + repack (fp32 -> fp16) ----------------
__global__ __launch_bounds__(256)
void convert_kernel(const float* __restrict__ Wg,
                    const float* __restrict__ W1,
                    const float* __restrict__ W2,
                    _Float16* __restrict__ ws)
{
    int i = blockIdx.x * 256 + threadIdx.x;
    if (i < 524288) {
        int k = i >> 10, c = i & 1023;
        if (k < 256) {
            ws[WGXP_OFF + (((size_t)(k >> 3) << 10) + c) * 8 + (k & 7)] = (_Float16)Wg[i];
        } else {
            int k2 = k - 256;
            ws[WGHP_OFF + (((size_t)(k2 >> 3) << 10) + c) * 8 + (k2 & 7)] = (_Float16)Wg[i];
        }
    } else if (i < 655360) {
        int j = i - 524288;           // W1 [4][H][F]
        int g = j >> 15, k = (j >> 7) & 255, f = j & 127;
        ws[W1P_OFF + (((size_t)((g << 5) + (k >> 3)) << 7) + f) * 8 + (k & 7)] = (_Float16)W1[j];
    } else if (i < 786432) {
        int j = i - 655360;           // W2 [4][F][H]
        int g = j >> 15, f = (j >> 8) & 127, h = j & 255;
        ws[W2P_OFF + (((size_t)((g << 4) + (f >> 3)) << 8) + h) * 8 + (f & 7)] = (_Float16)W2[j];
    }
}

// ---------------- main recurrence: one WG per batch element, chunked x-precompute ------
__global__ __launch_bounds__(1024)
void qlstm_chunk_kernel(const float* __restrict__ x,
                        const _Float16* __restrict__ ws,
                        const float* __restrict__ bg,
                        const float* __restrict__ b1,
                        const float* __restrict__ b2,
                        float* __restrict__ out)
{
    const int b   = blockIdx.x;
    const int tid = threadIdx.x;

    __shared__ __align__(16) _Float16 xc[CHUNK * DIM];      // x chunk, fp16 (8 KB)
    __shared__ __align__(16) _Float16 zxc[CHUNK * 1024];    // x-part of z + bg (32 KB)
    __shared__ __align__(16) _Float16 zh[1024];             // z fp16 (2 KB)
    __shared__ __align__(16) _Float16 h1h[512];             // FFN hidden fp16 (1 KB)
    __shared__ __align__(16) _Float16 ch2buf[HID];          // h(t-1) fp16 (512 B)
    __shared__ float z2buf[1024];                           // FFN out fp32 (4 KB)
    __shared__ float cbuf[HID];                             // cell state (1 KB)
    __shared__ float hbuf[HID];                             // last h fp32 (1 KB)

    // per-thread bias registers
    const float rbg = bg[tid];                              // col tid of stacked gates
    const float rb1 = (tid < 512) ? b1[tid] : 0.0f;         // [4][F] flat
    const float rb2 = b2[tid];                              // [4][H] flat

    if (tid < HID) { cbuf[tid] = 0.0f; hbuf[tid] = 0.0f; ch2buf[tid] = (_Float16)0.0f; }

    const uint4* __restrict__ wgxp = reinterpret_cast<const uint4*>(ws + WGXP_OFF);
    const uint4* __restrict__ wghp = reinterpret_cast<const uint4*>(ws + WGHP_OFF);
    const uint4* __restrict__ w1p  = reinterpret_cast<const uint4*>(ws + W1P_OFF);
    const uint4* __restrict__ w2p  = reinterpret_cast<const uint4*>(ws + W2P_OFF);
    const h2* ch2 = reinterpret_cast<const h2*>(ch2buf);
    const U4H* xcv = reinterpret_cast<const U4H*>(xc);      // [CHUNK][DIM/8]

    for (int t0 = 0; t0 < T_STEPS; t0 += CHUNK) {
        // ---- stage x chunk: CHUNK*DIM = 4096 floats, 4 per thread ----
        #pragma unroll
        for (int j = 0; j < (CHUNK * DIM) / 1024; ++j) {
            int idx = tid + j * 1024;
            int tl = idx >> 8, d = idx & 255;
            xc[tl * DIM + d] = (_Float16)x[((size_t)(t0 + tl) * BATCH + b) * DIM + d];
        }
        __syncthreads();

        // ---- chunk GEMM: zxc[tc][c] = bg[c] + sum_k xc[tc][k] * Wgx[k][c]; c = tid ----
        {
            float acc[CHUNK];
            #pragma unroll
            for (int tc = 0; tc < CHUNK; ++tc) acc[tc] = rbg;
            for (int k8 = 0; k8 < DIM / 8; ++k8) {          // 32 iters; Wgx streamed once/chunk
                U4H w; w.u = wgxp[(k8 << 10) + tid];
                #pragma unroll
                for (int tc = 0; tc < CHUNK; ++tc) {
                    U4H xv; xv.u = xcv[tc * (DIM / 8) + k8].u;   // wave-uniform b128 broadcast
                    acc[tc] = fdot2_(xv.h[0], w.h[0], acc[tc]);
                    acc[tc] = fdot2_(xv.h[1], w.h[1], acc[tc]);
                    acc[tc] = fdot2_(xv.h[2], w.h[2], acc[tc]);
                    acc[tc] = fdot2_(xv.h[3], w.h[3], acc[tc]);
                }
            }
            #pragma unroll
            for (int tc = 0; tc < CHUNK; ++tc) zxc[tc * 1024 + tid] = (_Float16)acc[tc];
        }
        __syncthreads();

        for (int tc = 0; tc < CHUNK; ++tc) {
            // ---- phase 1: z[c] = zx[c] + sum_k h[k]*Wgh[k][c]; c = tid ----
            {
                float acc = (float)zxc[tc * 1024 + tid];
                #pragma unroll 8
                for (int k8 = 0; k8 < HID / 8; ++k8) {      // 32 iters, 512 KB stream
                    U4H w; w.u = wghp[(k8 << 10) + tid];
                    acc = fdot2_(ch2[4 * k8 + 0], w.h[0], acc);
                    acc = fdot2_(ch2[4 * k8 + 1], w.h[1], acc);
                    acc = fdot2_(ch2[4 * k8 + 2], w.h[2], acc);
                    acc = fdot2_(ch2[4 * k8 + 3], w.h[3], acc);
                }
                zh[tid] = (_Float16)acc;
            }
            __syncthreads();

            // ---- phase 2: h1[g][f] = relu(sum_k z[g][k]*W1[g][k][f] + b1); tid<512 ----
            if (tid < 512) {
                const int g = tid >> 7, f = tid & 127;
                const h2* zp = reinterpret_cast<const h2*>(zh + (g << 8));
                float acc = rb1;
                #pragma unroll 8
                for (int k8 = 0; k8 < HID / 8; ++k8) {
                    U4H w; w.u = w1p[(((g << 5) + k8) << 7) + f];
                    acc = fdot2_(zp[4 * k8 + 0], w.h[0], acc);
                    acc = fdot2_(zp[4 * k8 + 1], w.h[1], acc);
                    acc = fdot2_(zp[4 * k8 + 2], w.h[2], acc);
                    acc = fdot2_(zp[4 * k8 + 3], w.h[3], acc);
                }
                h1h[tid] = (_Float16)fmaxf(acc, 0.0f);
            }
            __syncthreads();

            // ---- phase 3: z2[g][h] = sum_f h1[g][f]*W2[g][f][h] + b2 ----
            {
                const int g = tid >> 8, hcol = tid & 255;
                const h2* hp = reinterpret_cast<const h2*>(h1h + (g << 7));
                float acc = rb2;
                #pragma unroll 8
                for (int f8 = 0; f8 < FF / 8; ++f8) {       // 16 iters
                    U4H w; w.u = w2p[(((g << 4) + f8) << 8) + hcol];
                    acc = fdot2_(hp[4 * f8 + 0], w.h[0], acc);
                    acc = fdot2_(hp[4 * f8 + 1], w.h[1], acc);
                    acc = fdot2_(hp[4 * f8 + 2], w.h[2], acc);
                    acc = fdot2_(hp[4 * f8 + 3], w.h[3], acc);
                }
                z2buf[tid] = acc;
            }
            __syncthreads();

            // ---- gate update (threads 0..255) ----
            if (tid < HID) {
                float zf = z2buf[tid];
                float zi = z2buf[HID + tid];
                float zg = z2buf[2 * HID + tid];
                float zo = z2buf[3 * HID + tid];
                float fg = sigmoidf_(zf);
                float ig = sigmoidf_(zi);
                float gg = tanhf_(zg);
                float og = sigmoidf_(zo);
                float c  = fmaf(fg, cbuf[tid], ig * gg);
                float hh = og * tanhf_(c);
                cbuf[tid] = c;
                hbuf[tid] = hh;
                ch2buf[tid] = (_Float16)hh;
                out[((size_t)(t0 + tc) * BATCH + b) * HID + tid] = hh;
            }
            __syncthreads();
        }
    }

    if (tid < HID) {
        const size_t TBH = (size_t)T_STEPS * BATCH * HID;
        out[TBH + (size_t)b * HID + tid] = hbuf[tid];
        out[TBH + (size_t)BATCH * HID + (size_t)b * HID + tid] = cbuf[tid];
    }
}

// ---------------- fp32 fallback (round-1 kernel) if ws is too small ----------------
__global__ __launch_bounds__(512)
void qlstm_fp32_kernel(const float* __restrict__ x,
                       const float* __restrict__ Wg,
                       const float* __restrict__ bg,
                       const float* __restrict__ W1,
                       const float* __restrict__ b1,
                       const float* __restrict__ W2,
                       const float* __restrict__ b2,
                       float* __restrict__ out)
{
    const int b   = blockIdx.x;
    const int tid = threadIdx.x;

    __shared__ float comb[DIM + HID];
    __shared__ float zbuf[4 * HID];
    __shared__ float h1buf[4 * FF];
    __shared__ float z2buf[4 * HID];
    __shared__ float cbuf[HID];
    __shared__ float bgs[4 * HID];
    __shared__ float b1s[4 * FF];
    __shared__ float b2s[4 * HID];

    for (int i = tid; i < 4 * HID; i += 512) bgs[i] = bg[i];
    b1s[tid] = b1[tid];
    for (int i = tid; i < 4 * HID; i += 512) b2s[i] = b2[i];
    if (tid < HID) { cbuf[tid] = 0.0f; comb[DIM + tid] = 0.0f; }

    const float2* __restrict__ wgv = reinterpret_cast<const float2*>(Wg);

    for (int t = 0; t < T_STEPS; ++t) {
        __syncthreads();
        if (tid < DIM) comb[tid] = x[((size_t)t * BATCH + b) * DIM + tid];
        __syncthreads();

        float a0 = bgs[2 * tid], a1 = bgs[2 * tid + 1];
        {
            const float4* combv = reinterpret_cast<const float4*>(comb);
            #pragma unroll 4
            for (int k4 = 0; k4 < (DIM + HID) / 4; ++k4) {
                float4 cv = combv[k4];
                float2 w0 = wgv[(4 * k4 + 0) * 512 + tid];
                float2 w1 = wgv[(4 * k4 + 1) * 512 + tid];
                float2 w2 = wgv[(4 * k4 + 2) * 512 + tid];
                float2 w3 = wgv[(4 * k4 + 3) * 512 + tid];
                a0 = fmaf(cv.x, w0.x, a0); a1 = fmaf(cv.x, w0.y, a1);
                a0 = fmaf(cv.y, w1.x, a0); a1 = fmaf(cv.y, w1.y, a1);
                a0 = fmaf(cv.z, w2.x, a0); a1 = fmaf(cv.z, w2.y, a1);
                a0 = fmaf(cv.w, w3.x, a0); a1 = fmaf(cv.w, w3.y, a1);
            }
        }
        zbuf[2 * tid] = a0;
        zbuf[2 * tid + 1] = a1;
        __syncthreads();

        {
            const int g = tid >> 7, f = tid & 127;
            const float* __restrict__ w1q = W1 + (size_t)g * HID * FF + f;
            const float4* zv = reinterpret_cast<const float4*>(zbuf + g * HID);
            float acc = b1s[tid];
            #pragma unroll 4
            for (int h4 = 0; h4 < HID / 4; ++h4) {
                float4 z4 = zv[h4];
                acc = fmaf(z4.x, w1q[(4 * h4 + 0) * FF], acc);
                acc = fmaf(z4.y, w1q[(4 * h4 + 1) * FF], acc);
                acc = fmaf(z4.z, w1q[(4 * h4 + 2) * FF], acc);
                acc = fmaf(z4.w, w1q[(4 * h4 + 3) * FF], acc);
            }
            h1buf[tid] = fmaxf(acc, 0.0f);
        }
        __syncthreads();

        {
            const int h  = tid & 255;
            const int g0 = (tid >> 8) << 1;
            const float* __restrict__ w2a = W2 + (size_t)g0 * FF * HID + h;
            const float* __restrict__ w2b = w2a + FF * HID;
            const float4* h1va = reinterpret_cast<const float4*>(h1buf + g0 * FF);
            const float4* h1vb = reinterpret_cast<const float4*>(h1buf + (g0 + 1) * FF);
            float acc0 = b2s[g0 * HID + h];
            float acc1 = b2s[(g0 + 1) * HID + h];
            #pragma unroll 4
            for (int f4 = 0; f4 < FF / 4; ++f4) {
                float4 ha = h1va[f4], hb = h1vb[f4];
                acc0 = fmaf(ha.x, w2a[(4 * f4 + 0) * HID], acc0);
                acc0 = fmaf(ha.y, w2a[(4 * f4 + 1) * HID], acc0);
                acc0 = fmaf(ha.z, w2a[(4 * f4 + 2) * HID], acc0);
                acc0 = fmaf(ha.w, w2a[(4 * f4 + 3) * HID], acc0);
                acc1 = fmaf(hb.x, w2b[(4 * f4 + 0) * HID], acc1);
                acc1 = fmaf(hb.y, w2b[(4 * f4 + 1) * HID], acc1);
                acc1 = fmaf(hb.z, w2b[(4 * f4 + 2) * HID], acc1);
                acc1 = fmaf(hb.w, w2b[(4 * f4 + 3) * HID], acc1);
            }
            z2buf[g0 * HID + h] = acc0;
            z2buf[(g0 + 1) * HID + h] = acc1;
        }
        __syncthreads();

        if (tid < HID) {
            float zf = z2buf[tid];
            float zi = z2buf[HID + tid];
            float zg = z2buf[2 * HID + tid];
            float zo = z2buf[3 * HID + tid];
            float fg = sigmoidf_(zf);
            float ig = sigmoidf_(zi);
            float gg = tanhf_(zg);
            float og = sigmoidf_(zo);
            float c  = fmaf(fg, cbuf[tid], ig * gg);
            float hh = og * tanhf_(c);
            cbuf[tid] = c;
            comb[DIM + tid] = hh;
            out[((size_t)t * BATCH + b) * HID + tid] = hh;
        }
    }

    __syncthreads();
    if (tid < HID) {
        out[(size_t)T_STEPS * BATCH * HID + (size_t)b * HID + tid] = comb[DIM + tid];
        out[(size_t)T_STEPS * BATCH * HID + (size_t)BATCH * HID + (size_t)b * HID + tid] = cbuf[tid];
    }
}

extern "C" void kernel_launch(void* const* d_in, const int* in_sizes, int n_in,
                              void* d_out, int out_size, void* d_ws, size_t ws_size,
                              hipStream_t stream) {
    const float* x  = (const float*)d_in[0];
    const float* Wg = (const float*)d_in[1];
    const float* bg = (const float*)d_in[2];
    const float* W1 = (const float*)d_in[3];
    const float* b1 = (const float*)d_in[4];
    const float* W2 = (const float*)d_in[5];
    const float* b2 = (const float*)d_in[6];
    float* out = (float*)d_out;

    if (ws_size >= (size_t)WS_HALFS * sizeof(_Float16)) {
        _Float16* ws = (_Float16*)d_ws;
        convert_kernel<<<WS_HALFS / 256, 256, 0, stream>>>(Wg, W1, W2, ws);
        qlstm_chunk_kernel<<<BATCH, 1024, 0, stream>>>(x, ws, bg, b1, b2, out);
    } else {
        qlstm_fp32_kernel<<<BATCH, 512, 0, stream>>>(x, Wg, bg, W1, b1, W2, b2, out);
    }
}

// Round 5
// 7210.265 us; speedup vs baseline: 6.6989x; 1.2955x over previous
//
#include <hip/hip_runtime.h>
#include <hip/hip_fp16.h>
#include <cstdint>

#define T_STEPS 1024
#define BATCH   128
#define DIM     256   // D
#define HID     256   // H
#define FF      128   // F
#define CHUNK   16

typedef _Float16 h2 __attribute__((ext_vector_type(2)));

// ws layout:
//   fp16 packed weights (units _Float16):
//     WgxP at 0      : [256/8][1024][8] = 262144 halfs (512 KB)  rows k<256 of Wg
//     WghP at 262144 : [256/8][1024][8] = 262144 halfs (512 KB)  rows k>=256
//     W1P  at 524288 : [4][H/8][F][8]   = 131072 halfs (256 KB)
//     W2P  at 655360 : [4][F/8][H][8]   = 131072 halfs (256 KB)
//   z2 exchange (uint, tag<<16 | fp16): [128 b][4 g][2 p][256 c] at byte 1572864 (1 MB)
#define WGXP_OFF 0
#define WGHP_OFF 262144
#define W1P_OFF  524288
#define W2P_OFF  655360
#define WS_HALFS 786432
#define EX_BYTE_OFF 1572864
#define EX_WORDS    262144
#define WS_SPLIT4_BYTES (EX_BYTE_OFF + EX_WORDS * 4)   // ~2.62 MB

__device__ __forceinline__ float sigmoidf_(float x) {
    return 1.0f / (1.0f + __expf(-x));
}
__device__ __forceinline__ float tanhf_(float x) {
    float e = __expf(2.0f * x);
    return 1.0f - 2.0f / (e + 1.0f);
}
__device__ __forceinline__ float fdot2_(h2 a, h2 b, float c) {
#if __has_builtin(__builtin_amdgcn_fdot2)
    return __builtin_amdgcn_fdot2(a, b, c, false);
#else
    return fmaf((float)a.x, (float)b.x, fmaf((float)a.y, (float)b.y, c));
#endif
}

union U4H { uint4 u; h2 h[4]; };
union HU  { unsigned short u; _Float16 h; };

// ---------------- weight convert + repack (fp32 -> fp16) ----------------
__global__ __launch_bounds__(256)
void convert_kernel(const float* __restrict__ Wg,
                    const float* __restrict__ W1,
                    const float* __restrict__ W2,
                    _Float16* __restrict__ ws)
{
    int i = blockIdx.x * 256 + threadIdx.x;
    if (i < 524288) {
        int k = i >> 10, c = i & 1023;
        if (k < 256) {
            ws[WGXP_OFF + (((size_t)(k >> 3) << 10) + c) * 8 + (k & 7)] = (_Float16)Wg[i];
        } else {
            int k2 = k - 256;
            ws[WGHP_OFF + (((size_t)(k2 >> 3) << 10) + c) * 8 + (k2 & 7)] = (_Float16)Wg[i];
        }
    } else if (i < 655360) {
        int j = i - 524288;           // W1 [4][H][F]
        int g = j >> 15, k = (j >> 7) & 255, f = j & 127;
        ws[W1P_OFF + (((size_t)((g << 5) + (k >> 3)) << 7) + f) * 8 + (k & 7)] = (_Float16)W1[j];
    } else if (i < 786432) {
        int j = i - 655360;           // W2 [4][F][H]
        int g = j >> 15, f = (j >> 8) & 127, h = j & 255;
        ws[W2P_OFF + (((size_t)((g << 4) + (f >> 3)) << 8) + h) * 8 + (f & 7)] = (_Float16)W2[j];
    }
}

__global__ __launch_bounds__(512)
void exinit_kernel(unsigned* __restrict__ ex) {
    int i = blockIdx.x * 512 + threadIdx.x;
    if (i < EX_WORDS) ex[i] = 0u;     // tag 0 != any t+1 >= 1
}

// ---------------- 4-way gate split: blk = g*64 + bp; WG handles batches bp, bp+64 -----
// All relaxed agent atomics; NO fences (R3 lesson: acquire/release flushes L2 weights).
__global__ __launch_bounds__(512)
void qlstm_split4_kernel(const float* __restrict__ x,
                         const _Float16* __restrict__ ws,
                         unsigned* ex,
                         const float* __restrict__ bg,
                         const float* __restrict__ b1,
                         const float* __restrict__ b2,
                         float* __restrict__ out)
{
    const int blk = blockIdx.x;
    const int g   = blk >> 6;          // gate 0..3
    const int bp  = blk & 63;          // batch pair
    const int tid = threadIdx.x;
    const int bl  = tid >> 8;          // local batch 0/1
    const int b   = bp + (bl << 6);    // actual batch
    const int c   = tid & 255;         // column within gate

    __shared__ __align__(16) _Float16 xc[2 * CHUNK * DIM];     // 16 KB
    __shared__ __align__(16) _Float16 zxc[2 * CHUNK * 256];    // 16 KB
    __shared__ __align__(16) _Float16 zh[2 * 256];             // 1 KB
    __shared__ __align__(16) _Float16 h1h[2 * FF];             // 0.5 KB
    __shared__ __align__(16) _Float16 ch2buf[2 * 256];         // 1 KB  h(t-1) fp16

    const float rbg = bg[(g << 8) + c];
    const float rb2 = b2[(g << 8) + c];
    const float rb1 = b1[(g << 7) + (tid & 127)];
    float c_reg = 0.0f;                 // this thread's cell entry (bl, c)
    ch2buf[tid] = (_Float16)0.0f;

    const uint4* __restrict__ wgxp = reinterpret_cast<const uint4*>(ws + WGXP_OFF);
    const uint4* __restrict__ wghp = reinterpret_cast<const uint4*>(ws + WGHP_OFF);
    const uint4* __restrict__ w1p  = reinterpret_cast<const uint4*>(ws + W1P_OFF);
    const uint4* __restrict__ w2p  = reinterpret_cast<const uint4*>(ws + W2P_OFF);
    const h2* ch2 = reinterpret_cast<const h2*>(ch2buf);
    const U4H* xcv = reinterpret_cast<const U4H*>(xc);

    for (int t0 = 0; t0 < T_STEPS; t0 += CHUNK) {
        // ---- stage x chunk: 2 batches x 16 steps x 256 dims ----
        __syncthreads();
        #pragma unroll
        for (int j = 0; j < (2 * CHUNK * DIM) / 512; ++j) {     // 16 iters
            int idx = j * 512 + tid;
            int sb = idx >> 12, rem = idx & 4095;
            int tl = rem >> 8, d = rem & 255;
            xc[sb * 4096 + tl * 256 + d] =
                (_Float16)x[((size_t)(t0 + tl) * BATCH + bp + (sb << 6)) * DIM + d];
        }
        __syncthreads();

        // ---- chunk GEMM: zxc[bl][tc][c] = bg + sum_k xc[bl][tc][k] * Wgx[k][g*256+c] ----
        {
            float acc[CHUNK];
            #pragma unroll
            for (int tc = 0; tc < CHUNK; ++tc) acc[tc] = rbg;
            for (int k8 = 0; k8 < DIM / 8; ++k8) {              // 32 iters
                U4H w; w.u = wgxp[(k8 << 10) + (g << 8) + c];
                #pragma unroll
                for (int tc = 0; tc < CHUNK; ++tc) {
                    U4H xv; xv.u = xcv[bl * 512 + tc * 32 + k8].u;
                    acc[tc] = fdot2_(xv.h[0], w.h[0], acc[tc]);
                    acc[tc] = fdot2_(xv.h[1], w.h[1], acc[tc]);
                    acc[tc] = fdot2_(xv.h[2], w.h[2], acc[tc]);
                    acc[tc] = fdot2_(xv.h[3], w.h[3], acc[tc]);
                }
            }
            #pragma unroll
            for (int tc = 0; tc < CHUNK; ++tc)
                zxc[bl * 4096 + tc * 256 + c] = (_Float16)acc[tc];
        }
        __syncthreads();

        for (int tc = 0; tc < CHUNK; ++tc) {
            const int t = t0 + tc;
            const int p = t & 1;

            // ---- phase 1: z[g][c] = zx + sum_k h[k] * Wgh[k][g*256+c] ----
            {
                float acc = (float)zxc[bl * 4096 + tc * 256 + c];
                #pragma unroll 8
                for (int k8 = 0; k8 < HID / 8; ++k8) {          // 32 iters
                    U4H w; w.u = wghp[(k8 << 10) + (g << 8) + c];
                    acc = fdot2_(ch2[bl * 128 + 4 * k8 + 0], w.h[0], acc);
                    acc = fdot2_(ch2[bl * 128 + 4 * k8 + 1], w.h[1], acc);
                    acc = fdot2_(ch2[bl * 128 + 4 * k8 + 2], w.h[2], acc);
                    acc = fdot2_(ch2[bl * 128 + 4 * k8 + 3], w.h[3], acc);
                }
                zh[bl * 256 + c] = (_Float16)acc;
            }
            __syncthreads();

            // ---- phase 2: h1[bl][f] = relu(sum_k z[k] * W1[g][k][f] + b1) ----
            if ((tid & 255) < 128) {
                const int f = tid & 127;
                const h2* zp = reinterpret_cast<const h2*>(zh + bl * 256);
                float acc = rb1;
                #pragma unroll 8
                for (int k8 = 0; k8 < HID / 8; ++k8) {
                    U4H w; w.u = w1p[(((g << 5) + k8) << 7) + f];
                    acc = fdot2_(zp[4 * k8 + 0], w.h[0], acc);
                    acc = fdot2_(zp[4 * k8 + 1], w.h[1], acc);
                    acc = fdot2_(zp[4 * k8 + 2], w.h[2], acc);
                    acc = fdot2_(zp[4 * k8 + 3], w.h[3], acc);
                }
                h1h[bl * FF + f] = (_Float16)fmaxf(acc, 0.0f);
            }
            __syncthreads();

            // ---- phase 3: z2[c] = sum_f h1[f] * W2[g][f][c] + b2 -> publish tagged ----
            {
                const h2* hp = reinterpret_cast<const h2*>(h1h + bl * FF);
                float acc = rb2;
                #pragma unroll 8
                for (int f8 = 0; f8 < FF / 8; ++f8) {           // 16 iters
                    U4H w; w.u = w2p[(((g << 4) + f8) << 8) + c];
                    acc = fdot2_(hp[4 * f8 + 0], w.h[0], acc);
                    acc = fdot2_(hp[4 * f8 + 1], w.h[1], acc);
                    acc = fdot2_(hp[4 * f8 + 2], w.h[2], acc);
                    acc = fdot2_(hp[4 * f8 + 3], w.h[3], acc);
                }
                HU hu; hu.h = (_Float16)acc;
                unsigned word = ((unsigned)(t + 1) << 16) | (unsigned)hu.u;
                unsigned idx = (unsigned)(b * 2048 + g * 512 + p * 256 + c);
                __hip_atomic_store(&ex[idx], word, __ATOMIC_RELAXED, __HIP_MEMORY_SCOPE_AGENT);
            }

            // ---- gate update: spin on 4 tagged words (incl. own), all relaxed ----
            {
                const unsigned base = (unsigned)(b * 2048 + p * 256 + c);
                const unsigned want = (unsigned)(t + 1) << 16;
                unsigned w0, w1, w2, w3;
                for (;;) {
                    w0 = __hip_atomic_load(&ex[base],        __ATOMIC_RELAXED, __HIP_MEMORY_SCOPE_AGENT);
                    w1 = __hip_atomic_load(&ex[base + 512],  __ATOMIC_RELAXED, __HIP_MEMORY_SCOPE_AGENT);
                    w2 = __hip_atomic_load(&ex[base + 1024], __ATOMIC_RELAXED, __HIP_MEMORY_SCOPE_AGENT);
                    w3 = __hip_atomic_load(&ex[base + 1536], __ATOMIC_RELAXED, __HIP_MEMORY_SCOPE_AGENT);
                    unsigned m = ((w0 ^ want) | (w1 ^ want) | (w2 ^ want) | (w3 ^ want)) & 0xFFFF0000u;
                    if (m == 0u) break;
                    __builtin_amdgcn_s_sleep(1);
                }
                HU hf, hi, hg, ho;
                hf.u = (unsigned short)(w0 & 0xFFFFu);
                hi.u = (unsigned short)(w1 & 0xFFFFu);
                hg.u = (unsigned short)(w2 & 0xFFFFu);
                ho.u = (unsigned short)(w3 & 0xFFFFu);
                float fg = sigmoidf_((float)hf.h);
                float ig = sigmoidf_((float)hi.h);
                float gg = tanhf_((float)hg.h);
                float og = sigmoidf_((float)ho.h);
                c_reg = fmaf(fg, c_reg, ig * gg);
                float hh = og * tanhf_(c_reg);
                ch2buf[bl * 256 + c] = (_Float16)hh;
                if (g == 0) {
                    out[((size_t)t * BATCH + b) * HID + c] = hh;
                    if (t == T_STEPS - 1) {
                        const size_t TBH = (size_t)T_STEPS * BATCH * HID;
                        out[TBH + (size_t)b * HID + c] = hh;
                        out[TBH + (size_t)BATCH * HID + (size_t)b * HID + c] = c_reg;
                    }
                }
            }
            __syncthreads();
        }
    }
}

// ---------------- fallback: R4 chunk kernel (one WG per batch element) ----------------
__global__ __launch_bounds__(1024)
void qlstm_chunk_kernel(const float* __restrict__ x,
                        const _Float16* __restrict__ ws,
                        const float* __restrict__ bg,
                        const float* __restrict__ b1,
                        const float* __restrict__ b2,
                        float* __restrict__ out)
{
    const int b   = blockIdx.x;
    const int tid = threadIdx.x;

    __shared__ __align__(16) _Float16 xc[CHUNK * DIM];
    __shared__ __align__(16) _Float16 zxc[CHUNK * 1024];
    __shared__ __align__(16) _Float16 zh[1024];
    __shared__ __align__(16) _Float16 h1h[512];
    __shared__ __align__(16) _Float16 ch2buf[HID];
    __shared__ float z2buf[1024];
    __shared__ float cbuf[HID];
    __shared__ float hbuf[HID];

    const float rbg = bg[tid];
    const float rb1 = (tid < 512) ? b1[tid] : 0.0f;
    const float rb2 = b2[tid];

    if (tid < HID) { cbuf[tid] = 0.0f; hbuf[tid] = 0.0f; ch2buf[tid] = (_Float16)0.0f; }

    const uint4* __restrict__ wgxp = reinterpret_cast<const uint4*>(ws + WGXP_OFF);
    const uint4* __restrict__ wghp = reinterpret_cast<const uint4*>(ws + WGHP_OFF);
    const uint4* __restrict__ w1p  = reinterpret_cast<const uint4*>(ws + W1P_OFF);
    const uint4* __restrict__ w2p  = reinterpret_cast<const uint4*>(ws + W2P_OFF);
    const h2* ch2 = reinterpret_cast<const h2*>(ch2buf);
    const U4H* xcv = reinterpret_cast<const U4H*>(xc);

    for (int t0 = 0; t0 < T_STEPS; t0 += CHUNK) {
        #pragma unroll
        for (int j = 0; j < (CHUNK * DIM) / 1024; ++j) {
            int idx = tid + j * 1024;
            int tl = idx >> 8, d = idx & 255;
            xc[tl * DIM + d] = (_Float16)x[((size_t)(t0 + tl) * BATCH + b) * DIM + d];
        }
        __syncthreads();

        {
            float acc[CHUNK];
            #pragma unroll
            for (int tc = 0; tc < CHUNK; ++tc) acc[tc] = rbg;
            for (int k8 = 0; k8 < DIM / 8; ++k8) {
                U4H w; w.u = wgxp[(k8 << 10) + tid];
                #pragma unroll
                for (int tc = 0; tc < CHUNK; ++tc) {
                    U4H xv; xv.u = xcv[tc * (DIM / 8) + k8].u;
                    acc[tc] = fdot2_(xv.h[0], w.h[0], acc[tc]);
                    acc[tc] = fdot2_(xv.h[1], w.h[1], acc[tc]);
                    acc[tc] = fdot2_(xv.h[2], w.h[2], acc[tc]);
                    acc[tc] = fdot2_(xv.h[3], w.h[3], acc[tc]);
                }
            }
            #pragma unroll
            for (int tc = 0; tc < CHUNK; ++tc) zxc[tc * 1024 + tid] = (_Float16)acc[tc];
        }
        __syncthreads();

        for (int tc = 0; tc < CHUNK; ++tc) {
            {
                float acc = (float)zxc[tc * 1024 + tid];
                #pragma unroll 8
                for (int k8 = 0; k8 < HID / 8; ++k8) {
                    U4H w; w.u = wghp[(k8 << 10) + tid];
                    acc = fdot2_(ch2[4 * k8 + 0], w.h[0], acc);
                    acc = fdot2_(ch2[4 * k8 + 1], w.h[1], acc);
                    acc = fdot2_(ch2[4 * k8 + 2], w.h[2], acc);
                    acc = fdot2_(ch2[4 * k8 + 3], w.h[3], acc);
                }
                zh[tid] = (_Float16)acc;
            }
            __syncthreads();

            if (tid < 512) {
                const int g = tid >> 7, f = tid & 127;
                const h2* zp = reinterpret_cast<const h2*>(zh + (g << 8));
                float acc = rb1;
                #pragma unroll 8
                for (int k8 = 0; k8 < HID / 8; ++k8) {
                    U4H w; w.u = w1p[(((g << 5) + k8) << 7) + f];
                    acc = fdot2_(zp[4 * k8 + 0], w.h[0], acc);
                    acc = fdot2_(zp[4 * k8 + 1], w.h[1], acc);
                    acc = fdot2_(zp[4 * k8 + 2], w.h[2], acc);
                    acc = fdot2_(zp[4 * k8 + 3], w.h[3], acc);
                }
                h1h[tid] = (_Float16)fmaxf(acc, 0.0f);
            }
            __syncthreads();

            {
                const int g = tid >> 8, hcol = tid & 255;
                const h2* hp = reinterpret_cast<const h2*>(h1h + (g << 7));
                float acc = rb2;
                #pragma unroll 8
                for (int f8 = 0; f8 < FF / 8; ++f8) {
                    U4H w; w.u = w2p[(((g << 4) + f8) << 8) + hcol];
                    acc = fdot2_(hp[4 * f8 + 0], w.h[0], acc);
                    acc = fdot2_(hp[4 * f8 + 1], w.h[1], acc);
                    acc = fdot2_(hp[4 * f8 + 2], w.h[2], acc);
                    acc = fdot2_(hp[4 * f8 + 3], w.h[3], acc);
                }
                z2buf[tid] = acc;
            }
            __syncthreads();

            if (tid < HID) {
                float zf = z2buf[tid];
                float zi = z2buf[HID + tid];
                float zg = z2buf[2 * HID + tid];
                float zo = z2buf[3 * HID + tid];
                float fg = sigmoidf_(zf);
                float ig = sigmoidf_(zi);
                float gg = tanhf_(zg);
                float og = sigmoidf_(zo);
                float cc = fmaf(fg, cbuf[tid], ig * gg);
                float hh = og * tanhf_(cc);
                cbuf[tid] = cc;
                hbuf[tid] = hh;
                ch2buf[tid] = (_Float16)hh;
                out[((size_t)(t0 + tc) * BATCH + b) * HID + tid] = hh;
            }
            __syncthreads();
        }
    }

    if (tid < HID) {
        const size_t TBH = (size_t)T_STEPS * BATCH * HID;
        out[TBH + (size_t)b * HID + tid] = hbuf[tid];
        out[TBH + (size_t)BATCH * HID + (size_t)b * HID + tid] = cbuf[tid];
    }
}

// ---------------- fp32 fallback (round-1) ----------------
__global__ __launch_bounds__(512)
void qlstm_fp32_kernel(const float* __restrict__ x,
                       const float* __restrict__ Wg,
                       const float* __restrict__ bg,
                       const float* __restrict__ W1,
                       const float* __restrict__ b1,
                       const float* __restrict__ W2,
                       const float* __restrict__ b2,
                       float* __restrict__ out)
{
    const int b   = blockIdx.x;
    const int tid = threadIdx.x;

    __shared__ float comb[DIM + HID];
    __shared__ float zbuf[4 * HID];
    __shared__ float h1buf[4 * FF];
    __shared__ float z2buf[4 * HID];
    __shared__ float cbuf[HID];
    __shared__ float bgs[4 * HID];
    __shared__ float b1s[4 * FF];
    __shared__ float b2s[4 * HID];

    for (int i = tid; i < 4 * HID; i += 512) bgs[i] = bg[i];
    b1s[tid] = b1[tid];
    for (int i = tid; i < 4 * HID; i += 512) b2s[i] = b2[i];
    if (tid < HID) { cbuf[tid] = 0.0f; comb[DIM + tid] = 0.0f; }

    const float2* __restrict__ wgv = reinterpret_cast<const float2*>(Wg);

    for (int t = 0; t < T_STEPS; ++t) {
        __syncthreads();
        if (tid < DIM) comb[tid] = x[((size_t)t * BATCH + b) * DIM + tid];
        __syncthreads();

        float a0 = bgs[2 * tid], a1 = bgs[2 * tid + 1];
        {
            const float4* combv = reinterpret_cast<const float4*>(comb);
            #pragma unroll 4
            for (int k4 = 0; k4 < (DIM + HID) / 4; ++k4) {
                float4 cv = combv[k4];
                float2 w0 = wgv[(4 * k4 + 0) * 512 + tid];
                float2 w1 = wgv[(4 * k4 + 1) * 512 + tid];
                float2 w2 = wgv[(4 * k4 + 2) * 512 + tid];
                float2 w3 = wgv[(4 * k4 + 3) * 512 + tid];
                a0 = fmaf(cv.x, w0.x, a0); a1 = fmaf(cv.x, w0.y, a1);
                a0 = fmaf(cv.y, w1.x, a0); a1 = fmaf(cv.y, w1.y, a1);
                a0 = fmaf(cv.z, w2.x, a0); a1 = fmaf(cv.z, w2.y, a1);
                a0 = fmaf(cv.w, w3.x, a0); a1 = fmaf(cv.w, w3.y, a1);
            }
        }
        zbuf[2 * tid] = a0;
        zbuf[2 * tid + 1] = a1;
        __syncthreads();

        {
            const int g = tid >> 7, f = tid & 127;
            const float* __restrict__ w1q = W1 + (size_t)g * HID * FF + f;
            const float4* zv = reinterpret_cast<const float4*>(zbuf + g * HID);
            float acc = b1s[tid];
            #pragma unroll 4
            for (int h4 = 0; h4 < HID / 4; ++h4) {
                float4 z4 = zv[h4];
                acc = fmaf(z4.x, w1q[(4 * h4 + 0) * FF], acc);
                acc = fmaf(z4.y, w1q[(4 * h4 + 1) * FF], acc);
                acc = fmaf(z4.z, w1q[(4 * h4 + 2) * FF], acc);
                acc = fmaf(z4.w, w1q[(4 * h4 + 3) * FF], acc);
            }
            h1buf[tid] = fmaxf(acc, 0.0f);
        }
        __syncthreads();

        {
            const int h  = tid & 255;
            const int g0 = (tid >> 8) << 1;
            const float* __restrict__ w2a = W2 + (size_t)g0 * FF * HID + h;
            const float* __restrict__ w2b = w2a + FF * HID;
            const float4* h1va = reinterpret_cast<const float4*>(h1buf + g0 * FF);
            const float4* h1vb = reinterpret_cast<const float4*>(h1buf + (g0 + 1) * FF);
            float acc0 = b2s[g0 * HID + h];
            float acc1 = b2s[(g0 + 1) * HID + h];
            #pragma unroll 4
            for (int f4 = 0; f4 < FF / 4; ++f4) {
                float4 ha = h1va[f4], hb = h1vb[f4];
                acc0 = fmaf(ha.x, w2a[(4 * f4 + 0) * HID], acc0);
                acc0 = fmaf(ha.y, w2a[(4 * f4 + 1) * HID], acc0);
                acc0 = fmaf(ha.z, w2a[(4 * f4 + 2) * HID], acc0);
                acc0 = fmaf(ha.w, w2a[(4 * f4 + 3) * HID], acc0);
                acc1 = fmaf(hb.x, w2b[(4 * f4 + 0) * HID], acc1);
                acc1 = fmaf(hb.y, w2b[(4 * f4 + 1) * HID], acc1);
                acc1 = fmaf(hb.z, w2b[(4 * f4 + 2) * HID], acc1);
                acc1 = fmaf(hb.w, w2b[(4 * f4 + 3) * HID], acc1);
            }
            z2buf[g0 * HID + h] = acc0;
            z2buf[(g0 + 1) * HID + h] = acc1;
        }
        __syncthreads();

        if (tid < HID) {
            float zf = z2buf[tid];
            float zi = z2buf[HID + tid];
            float zg = z2buf[2 * HID + tid];
            float zo = z2buf[3 * HID + tid];
            float fg = sigmoidf_(zf);
            float ig = sigmoidf_(zi);
            float gg = tanhf_(zg);
            float og = sigmoidf_(zo);
            float cc = fmaf(fg, cbuf[tid], ig * gg);
            float hh = og * tanhf_(cc);
            cbuf[tid] = cc;
            comb[DIM + tid] = hh;
            out[((size_t)t * BATCH + b) * HID + tid] = hh;
        }
    }

    __syncthreads();
    if (tid < HID) {
        out[(size_t)T_STEPS * BATCH * HID + (size_t)b * HID + tid] = comb[DIM + tid];
        out[(size_t)T_STEPS * BATCH * HID + (size_t)BATCH * HID + (size_t)b * HID + tid] = cbuf[tid];
    }
}

extern "C" void kernel_launch(void* const* d_in, const int* in_sizes, int n_in,
                              void* d_out, int out_size, void* d_ws, size_t ws_size,
                              hipStream_t stream) {
    const float* x  = (const float*)d_in[0];
    const float* Wg = (const float*)d_in[1];
    const float* bg = (const float*)d_in[2];
    const float* W1 = (const float*)d_in[3];
    const float* b1 = (const float*)d_in[4];
    const float* W2 = (const float*)d_in[5];
    const float* b2 = (const float*)d_in[6];
    float* out = (float*)d_out;
    char* wsc = (char*)d_ws;

    if (ws_size >= (size_t)WS_SPLIT4_BYTES) {
        _Float16* ws = (_Float16*)wsc;
        unsigned* ex = (unsigned*)(wsc + EX_BYTE_OFF);
        convert_kernel<<<WS_HALFS / 256, 256, 0, stream>>>(Wg, W1, W2, ws);
        exinit_kernel<<<EX_WORDS / 512, 512, 0, stream>>>(ex);
        qlstm_split4_kernel<<<256, 512, 0, stream>>>(x, ws, ex, bg, b1, b2, out);
    } else if (ws_size >= (size_t)WS_HALFS * sizeof(_Float16)) {
        _Float16* ws = (_Float16*)wsc;
        convert_kernel<<<WS_HALFS / 256, 256, 0, stream>>>(Wg, W1, W2, ws);
        qlstm_chunk_kernel<<<BATCH, 1024, 0, stream>>>(x, ws, bg, b1, b2, out);
    } else {
        qlstm_fp32_kernel<<<BATCH, 512, 0, stream>>>(x, Wg, bg, W1, b1, W2, b2, out);
    }
}